// Round 1
// baseline (216.510 us; speedup 1.0000x reference)
//
#include <hip/hip_runtime.h>
#include <math.h>

#define TOKENS 16384
#define DIM 4096
#define NE 64
#define BM 32
#define BK 64

// ws layout (float offsets):
//   [0:64)    denom[e]  = sum of masked gates per expert
//   [64:128)  proxy[e]  = sum of gate_scores per expert
//   [128:192) countf[e] = number of tokens selecting expert e (exact float adds of 1.0)
//   [256: 256+4*TOKENS) meta per token: {i0(bits), i1(bits), g0, g1} as float4

__global__ void init_kernel(float* ws) {
    int i = threadIdx.x;
    if (i < 192) ws[i] = 0.0f;
}

__global__ __launch_bounds__(256) void gate_main(const float* __restrict__ x,
                                                 const float* __restrict__ W,
                                                 const float* __restrict__ bias,
                                                 float* __restrict__ ws) {
    __shared__ float xs[BM][68];      // x tile, padded stride 68 (16B aligned, spreads banks)
    __shared__ float wt[BK][NE];      // W tile (k-major)
    __shared__ float lg[BM][66];      // logits for softmax phase
    __shared__ float tmax[BM], tinvsum[BM];
    __shared__ float pp[4][NE];

    const int tid  = threadIdx.x;
    const int tBase = blockIdx.x * BM;

    const int col  = tid & 15;        // expert group: experts col*4 .. col*4+3
    const int trow = tid >> 4;        // 0..15
    const int t0   = trow * 2;        // tokens t0, t0+1 (local)

    float acc[2][4];
    #pragma unroll
    for (int i = 0; i < 2; i++)
        #pragma unroll
        for (int j = 0; j < 4; j++) acc[i][j] = 0.0f;

    for (int k0 = 0; k0 < DIM; k0 += BK) {
        // W tile: 64x64 floats contiguous at W + k0*NE (row-major [k][e])
        {
            const float4* wsrc = (const float4*)(W + (size_t)k0 * NE);
            float4* wdst = (float4*)(&wt[0][0]);
            #pragma unroll
            for (int r = 0; r < 4; r++) wdst[tid + r * 256] = wsrc[tid + r * 256];
        }
        // x tile: rows tBase..tBase+31, cols k0..k0+63
        {
            int row = tid >> 4;       // 0..15
            int c4  = tid & 15;
            float4 v0 = *(const float4*)(x + (size_t)(tBase + row) * DIM + k0 + c4 * 4);
            float4 v1 = *(const float4*)(x + (size_t)(tBase + row + 16) * DIM + k0 + c4 * 4);
            *(float4*)(&xs[row][c4 * 4])      = v0;
            *(float4*)(&xs[row + 16][c4 * 4]) = v1;
        }
        __syncthreads();

        #pragma unroll
        for (int g = 0; g < 16; g++) {
            float a[2][4], bv[4][4];
            *(float4*)a[0] = *(const float4*)(&xs[t0][g * 4]);
            *(float4*)a[1] = *(const float4*)(&xs[t0 + 1][g * 4]);
            #pragma unroll
            for (int kk = 0; kk < 4; kk++)
                *(float4*)bv[kk] = *(const float4*)(&wt[g * 4 + kk][col * 4]);
            #pragma unroll
            for (int i = 0; i < 2; i++)
                #pragma unroll
                for (int kk = 0; kk < 4; kk++)
                    #pragma unroll
                    for (int j = 0; j < 4; j++)
                        acc[i][j] = fmaf(a[i][kk], bv[kk][j], acc[i][j]);
        }
        __syncthreads();
    }

    // bias + stash logits to LDS
    #pragma unroll
    for (int j = 0; j < 4; j++) {
        float bj = bias[col * 4 + j];
        lg[t0][col * 4 + j]     = acc[0][j] + bj;
        lg[t0 + 1][col * 4 + j] = acc[1][j] + bj;
    }
    __syncthreads();

    // per-token softmax + top-2 (threads 0..31, one token each)
    if (tid < BM) {
        const int t = tid;
        float m = -INFINITY;
        #pragma unroll
        for (int e = 0; e < NE; e++) m = fmaxf(m, lg[t][e]);
        float s = 0.0f;
        float v0 = -INFINITY, v1 = -INFINITY;
        int i0 = 0, i1 = 1;
        #pragma unroll
        for (int e = 0; e < NE; e++) {
            float l = lg[t][e];
            s += expf(l - m);
            if (l > v0) { v1 = v0; i1 = i0; v0 = l; i0 = e; }
            else if (l > v1) { v1 = l; i1 = e; }
        }
        float inv = 1.0f / s;
        tmax[t] = m; tinvsum[t] = inv;
        float g0 = expf(v0 - m) * inv;
        float g1 = expf(v1 - m) * inv;
        float4 mt;
        mt.x = __int_as_float(i0);
        mt.y = __int_as_float(i1);
        mt.z = g0; mt.w = g1;
        ((float4*)(ws + 256))[tBase + t] = mt;
        atomicAdd(&ws[i0], g0);
        atomicAdd(&ws[i1], g1);
        atomicAdd(&ws[128 + i0], 1.0f);
        atomicAdd(&ws[128 + i1], 1.0f);
    }
    __syncthreads();

    // per-expert gate-score partial sums (density_proxy numerator)
    {
        int e   = tid & 63;
        int grp = tid >> 6;   // 0..3, 8 tokens each
        float p = 0.0f;
        #pragma unroll
        for (int r = 0; r < 8; r++) {
            int t = grp * 8 + r;
            p += expf(lg[t][e] - tmax[t]) * tinvsum[t];
        }
        pp[grp][e] = p;
    }
    __syncthreads();
    if (tid < NE) {
        float s = pp[0][tid] + pp[1][tid] + pp[2][tid] + pp[3][tid];
        atomicAdd(&ws[64 + tid], s);
    }
}

__global__ __launch_bounds__(256) void gate_write(const float* __restrict__ ws,
                                                  float* __restrict__ out) {
    const float CAP = 16384.0f;
    int tid = threadIdx.x;
    int tl  = tid >> 4;                 // 16 tokens per block
    int e4  = (tid & 15) * 4;
    int t   = blockIdx.x * 16 + tl;
    float4 mt = ((const float4*)(ws + 256))[t];
    int i0 = __float_as_int(mt.x), i1 = __float_as_int(mt.y);
    float s0 = mt.z * CAP / (ws[i0] + 1e-6f);
    float s1 = mt.w * CAP / (ws[i1] + 1e-6f);
    float4 v = {0.0f, 0.0f, 0.0f, 0.0f};
    float* vp = (float*)&v;
    #pragma unroll
    for (int j = 0; j < 4; j++) {
        int e = e4 + j;
        vp[j] = (e == i0) ? s0 : ((e == i1) ? s1 : 0.0f);
    }
    *(float4*)(out + (size_t)t * NE + e4) = v;
}

__global__ void gate_loss(const float* __restrict__ ws, float* __restrict__ out) {
    int e = threadIdx.x;
    float v = ws[64 + e] * ws[128 + e];
    #pragma unroll
    for (int off = 32; off; off >>= 1) v += __shfl_down(v, off);
    if (e == 0) {
        out[(size_t)TOKENS * NE] = 64.0f * v / (16384.0f * 16384.0f);
    }
}

extern "C" void kernel_launch(void* const* d_in, const int* in_sizes, int n_in,
                              void* d_out, int out_size, void* d_ws, size_t ws_size,
                              hipStream_t stream) {
    const float* x  = (const float*)d_in[0];
    const float* W  = (const float*)d_in[1];
    const float* b  = (const float*)d_in[2];
    float* out = (float*)d_out;
    float* ws  = (float*)d_ws;

    hipLaunchKernelGGL(init_kernel, dim3(1), dim3(256), 0, stream, ws);
    hipLaunchKernelGGL(gate_main, dim3(TOKENS / BM), dim3(256), 0, stream, x, W, b, ws);
    hipLaunchKernelGGL(gate_write, dim3(TOKENS / 16), dim3(256), 0, stream, ws, out);
    hipLaunchKernelGGL(gate_loss, dim3(1), dim3(64), 0, stream, ws, out);
}

// Round 3
// 171.679 us; speedup vs baseline: 1.2611x; 1.2611x over previous
//
#include <hip/hip_runtime.h>
#include <math.h>

#define TOKENS 16384
#define DIM 4096
#define NE 64
#define BM 64
#define BK 64
#define NKT (DIM / BK)

// ws float offsets
#define WS_DENOM 0
#define WS_PROXY 64
#define WS_COUNT 128
#define WS_META  256            // float4 per token: 65536 floats
#define WS_WST   65792          // 3 planes x 262144 ushorts (hi/mid/lo, pre-swizzled)

typedef __attribute__((ext_vector_type(8))) short bf16x8;
typedef __attribute__((ext_vector_type(16))) float f32x16;

__device__ __forceinline__ ushort f2bf(float f) {
    uint u = __float_as_uint(f);
    return (ushort)((u + 0x7FFFu + ((u >> 16) & 1u)) >> 16);
}
__device__ __forceinline__ float bf2f(ushort h) {
    return __uint_as_float(((uint)h) << 16);
}
__device__ __forceinline__ void split3(float f, ushort& h, ushort& m, ushort& l) {
    h = f2bf(f);
    float r = f - bf2f(h);
    m = f2bf(r);
    r -= bf2f(m);
    l = f2bf(r);
}

__global__ void init_kernel(float* ws) {
    int i = threadIdx.x;
    if (i < 192) ws[i] = 0.0f;
}

// W [4096][64] f32 -> 3 bf16 planes, layout [plane][kt][e][chunk8] with the
// chunk index pre-XOR'd (chunk_stored = chunk_logical ^ (e&7)) so a linear
// global_load_lds copy lands in the swizzled LDS layout.
__global__ __launch_bounds__(256) void wconv(const float* __restrict__ W,
                                             ushort* __restrict__ wst) {
    __shared__ float t[64][68];
    const int kt = blockIdx.x;
    const int tid = threadIdx.x;
    #pragma unroll
    for (int i = 0; i < 4; i++) {
        int idx = tid + i * 256;          // float4 index 0..1023
        int r = idx >> 4, c4 = idx & 15;
        float4 v = *(const float4*)(W + (size_t)(kt * 64 + r) * NE + c4 * 4);
        *(float4*)(&t[r][c4 * 4]) = v;
    }
    __syncthreads();
    #pragma unroll
    for (int i = 0; i < 2; i++) {
        int idx = tid + i * 256;          // 0..511 = 64e x 8 chunks
        int e = idx >> 3, cl = idx & 7;
        int k0 = (cl ^ (e & 7)) * 8;      // logical k start within tile
        uint H[4], M[4], L[4];
        #pragma unroll
        for (int j = 0; j < 4; j++) {
            ushort h0, m0, l0, h1, m1, l1;
            split3(t[k0 + 2 * j][e], h0, m0, l0);
            split3(t[k0 + 2 * j + 1][e], h1, m1, l1);
            H[j] = (uint)h0 | ((uint)h1 << 16);
            M[j] = (uint)m0 | ((uint)m1 << 16);
            L[j] = (uint)l0 | ((uint)l1 << 16);
        }
        size_t o = (size_t)kt * 4096 + e * 64 + cl * 8;
        *(uint4*)(wst + o)          = make_uint4(H[0], H[1], H[2], H[3]);
        *(uint4*)(wst + 262144 + o) = make_uint4(M[0], M[1], M[2], M[3]);
        *(uint4*)(wst + 524288 + o) = make_uint4(L[0], L[1], L[2], L[3]);
    }
}

// LDS buffer (bytes): xh[0,8K) xm[8K,16K) xl[16K,24K) wh[24K,32K) wm[32K,40K) wl[40K,48K)
__global__ __launch_bounds__(512, 2) void gate_main(const float* __restrict__ x,
        const ushort* __restrict__ wst, const float* __restrict__ bias,
        float* __restrict__ ws) {

    __shared__ __align__(16) char smem[2][49152];
    __shared__ float lg[BM][66];
    __shared__ float tmax[BM], tinv[BM];
    __shared__ float pp[8][NE];

    const int tid = threadIdx.x;
    const int tBase = blockIdx.x * BM;
    const int wave = tid >> 6, lane = tid & 63;
    const int rh = wave >> 2;          // row half 0..1
    const int kq = wave & 3;           // K quarter 0..3
    const int l31 = lane & 31, hi = lane >> 5;

    // fragment read offsets (kt-independent); k of lane = kq*16 + hi*8 + i
    const int arow = rh * 32 + l31;
    const uint aoff  = (uint)arow * 128 + (uint)((((kq * 2 + hi) ^ (arow & 7))) * 16);
    const uint boff0 = (uint)l31 * 128 + (uint)((((kq * 2 + hi) ^ (l31 & 7))) * 16);
    const int brow1 = 32 + l31;
    const uint boff1 = (uint)brow1 * 128 + (uint)((((kq * 2 + hi) ^ (brow1 & 7))) * 16);

    // x staging indices
    const int srow = tid >> 3, sc8 = tid & 7;
    const uint xoff = (uint)srow * 128 + (uint)(((sc8 ^ (srow & 7))) * 16);

    f32x16 acc0, acc1;
    #pragma unroll
    for (int i = 0; i < 16; i++) { acc0[i] = 0.0f; acc1[i] = 0.0f; }

    auto stage = [&](int buf, int kt) {
        char* B = smem[buf];
        // ---- x: f32 load, 3-way bf16 split, swizzled ds_write_b128
        const float* xp = x + (size_t)(tBase + srow) * DIM + kt * BK + sc8 * 8;
        float4 v0 = *(const float4*)xp;
        float4 v1 = *(const float4*)(xp + 4);
        float fv[8] = {v0.x, v0.y, v0.z, v0.w, v1.x, v1.y, v1.z, v1.w};
        uint H[4], M[4], L[4];
        #pragma unroll
        for (int i = 0; i < 4; i++) {
            ushort h0, m0, l0, h1, m1, l1;
            split3(fv[2 * i], h0, m0, l0);
            split3(fv[2 * i + 1], h1, m1, l1);
            H[i] = (uint)h0 | ((uint)h1 << 16);
            M[i] = (uint)m0 | ((uint)m1 << 16);
            L[i] = (uint)l0 | ((uint)l1 << 16);
        }
        *(uint4*)(B + xoff)          = make_uint4(H[0], H[1], H[2], H[3]);
        *(uint4*)(B + 8192 + xoff)   = make_uint4(M[0], M[1], M[2], M[3]);
        *(uint4*)(B + 16384 + xoff)  = make_uint4(L[0], L[1], L[2], L[3]);
        // ---- W: pre-split pre-swizzled planes, direct global->LDS (16B)
        #pragma unroll
        for (int j = 0; j < 3; j++) {
            int ii = wave * 3 + j;         // 0..23
            int p = ii >> 3, rg = ii & 7;  // plane, 8-row group
            const ushort* src = wst + (size_t)p * 262144 + (size_t)kt * 4096
                              + rg * 512 + lane * 8;
            char* dst = B + 24576 + p * 8192 + rg * 1024 + lane * 16;
            __builtin_amdgcn_global_load_lds(
                (const __attribute__((address_space(1))) uint*)src,
                (__attribute__((address_space(3))) uint*)dst, 16, 0, 0);
        }
    };

    stage(0, 0);
    __syncthreads();

    for (int kt = 0; kt < NKT; kt++) {
        int cur = kt & 1;
        if (kt + 1 < NKT) stage(cur ^ 1, kt + 1);
        const char* B = smem[cur];
        bf16x8 xh = *(const bf16x8*)(B + aoff);
        bf16x8 xm = *(const bf16x8*)(B + 8192 + aoff);
        bf16x8 xl = *(const bf16x8*)(B + 16384 + aoff);
        const char* Wb = B + 24576;
        bf16x8 wh0 = *(const bf16x8*)(Wb + boff0);
        bf16x8 wh1 = *(const bf16x8*)(Wb + boff1);
        bf16x8 wm0 = *(const bf16x8*)(Wb + 8192 + boff0);
        bf16x8 wm1 = *(const bf16x8*)(Wb + 8192 + boff1);
        bf16x8 wl0 = *(const bf16x8*)(Wb + 16384 + boff0);
        bf16x8 wl1 = *(const bf16x8*)(Wb + 16384 + boff1);
        acc0 = __builtin_amdgcn_mfma_f32_32x32x16_bf16(xh, wh0, acc0, 0, 0, 0);
        acc1 = __builtin_amdgcn_mfma_f32_32x32x16_bf16(xh, wh1, acc1, 0, 0, 0);
        acc0 = __builtin_amdgcn_mfma_f32_32x32x16_bf16(xh, wm0, acc0, 0, 0, 0);
        acc1 = __builtin_amdgcn_mfma_f32_32x32x16_bf16(xh, wm1, acc1, 0, 0, 0);
        acc0 = __builtin_amdgcn_mfma_f32_32x32x16_bf16(xm, wh0, acc0, 0, 0, 0);
        acc1 = __builtin_amdgcn_mfma_f32_32x32x16_bf16(xm, wh1, acc1, 0, 0, 0);
        acc0 = __builtin_amdgcn_mfma_f32_32x32x16_bf16(xh, wl0, acc0, 0, 0, 0);
        acc1 = __builtin_amdgcn_mfma_f32_32x32x16_bf16(xh, wl1, acc1, 0, 0, 0);
        acc0 = __builtin_amdgcn_mfma_f32_32x32x16_bf16(xm, wm0, acc0, 0, 0, 0);
        acc1 = __builtin_amdgcn_mfma_f32_32x32x16_bf16(xm, wm1, acc1, 0, 0, 0);
        acc0 = __builtin_amdgcn_mfma_f32_32x32x16_bf16(xl, wh0, acc0, 0, 0, 0);
        acc1 = __builtin_amdgcn_mfma_f32_32x32x16_bf16(xl, wh1, acc1, 0, 0, 0);
        __syncthreads();
    }

    // cross-wave K reduction into lg (C/D: col=lane&31, row=(reg&3)+8*(reg>>2)+4*hi)
    {
        float b0 = bias[l31], b1 = bias[32 + l31];
        for (int p = 0; p < 4; p++) {
            if (kq == p) {
                #pragma unroll
                for (int reg = 0; reg < 16; reg++) {
                    int rl = (reg & 3) + 8 * (reg >> 2) + 4 * hi;
                    int grow = rh * 32 + rl;
                    if (p == 0) {
                        lg[grow][l31]      = acc0[reg] + b0;
                        lg[grow][32 + l31] = acc1[reg] + b1;
                    } else {
                        lg[grow][l31]      += acc0[reg];
                        lg[grow][32 + l31] += acc1[reg];
                    }
                }
            }
            __syncthreads();
        }
    }

    // per-token softmax + top-2 (threads 0..63, one token each)
    if (tid < BM) {
        const int t = tid;
        float m = -INFINITY;
        #pragma unroll
        for (int e = 0; e < NE; e++) m = fmaxf(m, lg[t][e]);
        float s = 0.0f;
        float v0 = -INFINITY, v1 = -INFINITY;
        int i0 = 0, i1 = 1;
        #pragma unroll
        for (int e = 0; e < NE; e++) {
            float l = lg[t][e];
            s += expf(l - m);
            if (l > v0) { v1 = v0; i1 = i0; v0 = l; i0 = e; }
            else if (l > v1) { v1 = l; i1 = e; }
        }
        float inv = 1.0f / s;
        tmax[t] = m; tinv[t] = inv;
        float g0 = expf(v0 - m) * inv;
        float g1 = expf(v1 - m) * inv;
        float4 mt4;
        mt4.x = __int_as_float(i0);
        mt4.y = __int_as_float(i1);
        mt4.z = g0; mt4.w = g1;
        ((float4*)(ws + WS_META))[tBase + t] = mt4;
        atomicAdd(&ws[WS_DENOM + i0], g0);
        atomicAdd(&ws[WS_DENOM + i1], g1);
        atomicAdd(&ws[WS_COUNT + i0], 1.0f);
        atomicAdd(&ws[WS_COUNT + i1], 1.0f);
    }
    __syncthreads();

    // per-expert gate-score partial sums (density_proxy numerator)
    {
        int e = tid & 63;
        int grp = tid >> 6;    // 0..7, 8 tokens each
        float p = 0.0f;
        #pragma unroll
        for (int r = 0; r < 8; r++) {
            int t = grp * 8 + r;
            p += expf(lg[t][e] - tmax[t]) * tinv[t];
        }
        pp[grp][e] = p;
    }
    __syncthreads();
    if (tid < NE) {
        float s = 0.0f;
        #pragma unroll
        for (int g = 0; g < 8; g++) s += pp[g][tid];
        atomicAdd(&ws[WS_PROXY + tid], s);
    }
}

__global__ __launch_bounds__(256) void gate_write(const float* __restrict__ ws,
                                                  float* __restrict__ out) {
    const float CAP = 16384.0f;
    int tid = threadIdx.x;
    int tl = tid >> 4;
    int e4 = (tid & 15) * 4;
    int t = blockIdx.x * 16 + tl;
    float4 mt = ((const float4*)(ws + WS_META))[t];
    int i0 = __float_as_int(mt.x), i1 = __float_as_int(mt.y);
    float s0 = mt.z * CAP / (ws[i0] + 1e-6f);
    float s1 = mt.w * CAP / (ws[i1] + 1e-6f);
    float4 v = {0.0f, 0.0f, 0.0f, 0.0f};
    float* vp = (float*)&v;
    #pragma unroll
    for (int j = 0; j < 4; j++) {
        int e = e4 + j;
        vp[j] = (e == i0) ? s0 : ((e == i1) ? s1 : 0.0f);
    }
    *(float4*)(out + (size_t)t * NE + e4) = v;
}

__global__ void gate_loss(const float* __restrict__ ws, float* __restrict__ out) {
    int e = threadIdx.x;
    float v = ws[WS_PROXY + e] * ws[WS_COUNT + e];
    #pragma unroll
    for (int off = 32; off; off >>= 1) v += __shfl_down(v, off);
    if (e == 0) {
        out[(size_t)TOKENS * NE] = 64.0f * v / (16384.0f * 16384.0f);
    }
}

extern "C" void kernel_launch(void* const* d_in, const int* in_sizes, int n_in,
                              void* d_out, int out_size, void* d_ws, size_t ws_size,
                              hipStream_t stream) {
    const float* x = (const float*)d_in[0];
    const float* W = (const float*)d_in[1];
    const float* b = (const float*)d_in[2];
    float* out = (float*)d_out;
    float* ws = (float*)d_ws;
    ushort* wst = (ushort*)(ws + WS_WST);

    hipLaunchKernelGGL(init_kernel, dim3(1), dim3(256), 0, stream, ws);
    hipLaunchKernelGGL(wconv, dim3(64), dim3(256), 0, stream, W, wst);
    hipLaunchKernelGGL(gate_main, dim3(TOKENS / BM), dim3(512), 0, stream,
                       x, wst, b, ws);
    hipLaunchKernelGGL(gate_write, dim3(TOKENS / 16), dim3(256), 0, stream, ws, out);
    hipLaunchKernelGGL(gate_loss, dim3(1), dim3(64), 0, stream, ws, out);
}